// Round 1
// baseline (1906.891 us; speedup 1.0000x reference)
//
#include <hip/hip_runtime.h>
#include <math.h>

#define N_PTS 32768
#define DIM   512
#define K_CL  64
#define ITERS 10
#define EPS_F 1e-8f

// ---------------------------------------------------------------------------
// ws layout (floats):
//   centers: [0, 32768)          64 x 512
//   sums:    [32768, 65536)      64 x 512
//   c2:      [65536, 65600)      64
//   counts:  int32 at float offset 65600, 64 ints
// d_out doubles as per-cluster index lists during iterations:
//   lists[k*32768 + slot]  (64*32768 ints == out_size elements exactly)
// ---------------------------------------------------------------------------

__global__ void init_centers(const float* __restrict__ x,
                             float* __restrict__ centers,
                             float* __restrict__ c2) {
    int k = blockIdx.x;      // 0..63
    int t = threadIdx.x;     // 0..255
    float ssum = 0.f;
    for (int d = t; d < DIM; d += 256) {
        float v = x[k * DIM + d];
        centers[k * DIM + d] = v;
        ssum += v * v;
    }
    #pragma unroll
    for (int off = 32; off; off >>= 1) ssum += __shfl_down(ssum, off);
    __shared__ float red[4];
    int wave = t >> 6, lane = t & 63;
    if (lane == 0) red[wave] = ssum;
    __syncthreads();
    if (t == 0) c2[k] = red[0] + red[1] + red[2] + red[3];
}

// 64 points x 64 clusters tile GEMM (dot products), argmin, scatter to lists.
__launch_bounds__(256)
__global__ void assign_scatter(const float* __restrict__ x,
                               const float* __restrict__ centers,
                               const float* __restrict__ c2,
                               int* __restrict__ counts,
                               int* __restrict__ lists) {
    __shared__ float xs[64 * 68];   // [dim_local][point], stride 68 keeps 16B align
    __shared__ float cs[64 * 68];   // [dim_local][cluster]
    __shared__ float c2s[K_CL];

    int tid = threadIdx.x;
    int pbase = blockIdx.x * 64;
    if (tid < K_CL) c2s[tid] = c2[tid];

    int r = tid >> 4;   // 0..15: point quad (compute) / row (staging)
    int c = tid & 15;   // 0..15: cluster quad (compute) / dim quad (staging)

    float acc[4][4];
    #pragma unroll
    for (int i = 0; i < 4; ++i)
        #pragma unroll
        for (int j = 0; j < 4; ++j) acc[i][j] = 0.f;

    for (int db = 0; db < DIM; db += 64) {
        __syncthreads();
        #pragma unroll
        for (int pass = 0; pass < 4; ++pass) {
            int p  = r + pass * 16;       // 0..63
            int dq = c * 4;               // 0..60
            float4 xv = *(const float4*)(x + (size_t)(pbase + p) * DIM + db + dq);
            float4 cv = *(const float4*)(centers + (size_t)p * DIM + db + dq);
            xs[(dq + 0) * 68 + p] = xv.x;
            xs[(dq + 1) * 68 + p] = xv.y;
            xs[(dq + 2) * 68 + p] = xv.z;
            xs[(dq + 3) * 68 + p] = xv.w;
            cs[(dq + 0) * 68 + p] = cv.x;
            cs[(dq + 1) * 68 + p] = cv.y;
            cs[(dq + 2) * 68 + p] = cv.z;
            cs[(dq + 3) * 68 + p] = cv.w;
        }
        __syncthreads();
        #pragma unroll 16
        for (int kk = 0; kk < 64; ++kk) {
            float4 xv = *(const float4*)(xs + kk * 68 + r * 4);
            float4 cv = *(const float4*)(cs + kk * 68 + c * 4);
            float xq[4] = {xv.x, xv.y, xv.z, xv.w};
            float cq[4] = {cv.x, cv.y, cv.z, cv.w};
            #pragma unroll
            for (int i = 0; i < 4; ++i)
                #pragma unroll
                for (int j = 0; j < 4; ++j)
                    acc[i][j] += xq[i] * cq[j];
        }
    }

    // argmin over clusters of (c2[k] - 2*dot)  (a2 is constant per point)
    #pragma unroll
    for (int i = 0; i < 4; ++i) {
        float bv = 1e30f; int bc = 0;
        #pragma unroll
        for (int j = 0; j < 4; ++j) {
            float v = c2s[c * 4 + j] - 2.0f * acc[i][j];
            if (v < bv) { bv = v; bc = c * 4 + j; }
        }
        #pragma unroll
        for (int m = 1; m < 16; m <<= 1) {
            float ov = __shfl_xor(bv, m);
            int   oc = __shfl_xor(bc, m);
            if (ov < bv || (ov == bv && oc < bc)) { bv = ov; bc = oc; }
        }
        if (c == 0) {
            int p = pbase + r * 4 + i;
            int slot = atomicAdd(&counts[bc], 1);
            lists[bc * N_PTS + slot] = p;
        }
    }
}

// Per (cluster, dim-chunk, point-chunk): register-accumulate gathered rows.
__global__ void gather_sums(const float* __restrict__ x,
                            const int* __restrict__ lists,
                            const int* __restrict__ counts,
                            float* __restrict__ sums) {
    int k  = blockIdx.x;   // 0..63
    int dc = blockIdx.y;   // 0..3
    int pc = blockIdx.z;   // 0..7
    int t  = threadIdx.x;  // 0..127
    int n  = counts[k];
    int s0 = (n * pc) >> 3;
    int s1 = (n * (pc + 1)) >> 3;
    int d  = dc * 128 + t;
    const int* lst = lists + k * N_PTS;
    float acc = 0.f;
    int s = s0;
    for (; s + 8 <= s1; s += 8) {
        int idx[8];
        #pragma unroll
        for (int q = 0; q < 8; ++q) idx[q] = lst[s + q];
        #pragma unroll
        for (int q = 0; q < 8; ++q) acc += x[(size_t)idx[q] * DIM + d];
    }
    for (; s < s1; ++s) acc += x[(size_t)lst[s] * DIM + d];
    atomicAdd(&sums[k * DIM + d], acc);
}

__global__ void update_centers(float* __restrict__ centers,
                               const float* __restrict__ sums,
                               const int* __restrict__ counts,
                               float* __restrict__ c2) {
    int k = blockIdx.x;
    int t = threadIdx.x;
    int cnt = counts[k];
    float fc = (float)cnt;
    float ssum = 0.f;
    for (int d = t; d < DIM; d += 256) {
        float v = centers[k * DIM + d];
        if (cnt > 0) v = sums[k * DIM + d] / fc;
        centers[k * DIM + d] = v;
        ssum += v * v;
    }
    #pragma unroll
    for (int off = 32; off; off >>= 1) ssum += __shfl_down(ssum, off);
    __shared__ float red[4];
    int wave = t >> 6, lane = t & 63;
    if (lane == 0) red[wave] = ssum;
    __syncthreads();
    if (t == 0) c2[k] = red[0] + red[1] + red[2] + red[3];
}

// Final distances via DIRECT differencing: exact 0 at singleton clusters.
__launch_bounds__(256)
__global__ void final_dist(const float* __restrict__ x,
                           const float* __restrict__ centers,
                           float* __restrict__ out) {
    __shared__ float xs[64 * 68];
    __shared__ float cs[64 * 68];

    int tid = threadIdx.x;
    int pbase = blockIdx.x * 64;
    int r = tid >> 4;
    int c = tid & 15;

    float acc[4][4];
    #pragma unroll
    for (int i = 0; i < 4; ++i)
        #pragma unroll
        for (int j = 0; j < 4; ++j) acc[i][j] = 0.f;

    for (int db = 0; db < DIM; db += 64) {
        __syncthreads();
        #pragma unroll
        for (int pass = 0; pass < 4; ++pass) {
            int p  = r + pass * 16;
            int dq = c * 4;
            float4 xv = *(const float4*)(x + (size_t)(pbase + p) * DIM + db + dq);
            float4 cv = *(const float4*)(centers + (size_t)p * DIM + db + dq);
            xs[(dq + 0) * 68 + p] = xv.x;
            xs[(dq + 1) * 68 + p] = xv.y;
            xs[(dq + 2) * 68 + p] = xv.z;
            xs[(dq + 3) * 68 + p] = xv.w;
            cs[(dq + 0) * 68 + p] = cv.x;
            cs[(dq + 1) * 68 + p] = cv.y;
            cs[(dq + 2) * 68 + p] = cv.z;
            cs[(dq + 3) * 68 + p] = cv.w;
        }
        __syncthreads();
        #pragma unroll 8
        for (int kk = 0; kk < 64; ++kk) {
            float4 xv = *(const float4*)(xs + kk * 68 + r * 4);
            float4 cv = *(const float4*)(cs + kk * 68 + c * 4);
            float xq[4] = {xv.x, xv.y, xv.z, xv.w};
            float cq[4] = {cv.x, cv.y, cv.z, cv.w};
            #pragma unroll
            for (int i = 0; i < 4; ++i)
                #pragma unroll
                for (int j = 0; j < 4; ++j) {
                    float dlt = xq[i] - cq[j];
                    acc[i][j] += dlt * dlt;
                }
        }
    }

    #pragma unroll
    for (int i = 0; i < 4; ++i) {
        int p = pbase + r * 4 + i;
        float4 o;
        o.x = 1.0f / (sqrtf(acc[i][0]) + EPS_F);
        o.y = 1.0f / (sqrtf(acc[i][1]) + EPS_F);
        o.z = 1.0f / (sqrtf(acc[i][2]) + EPS_F);
        o.w = 1.0f / (sqrtf(acc[i][3]) + EPS_F);
        *(float4*)(out + (size_t)p * K_CL + c * 4) = o;
    }
}

extern "C" void kernel_launch(void* const* d_in, const int* in_sizes, int n_in,
                              void* d_out, int out_size, void* d_ws, size_t ws_size,
                              hipStream_t stream) {
    (void)in_sizes; (void)n_in; (void)out_size; (void)ws_size;
    const float* x = (const float*)d_in[0];
    float* ws      = (float*)d_ws;
    float* centers = ws;
    float* sums    = ws + 32768;
    float* c2      = ws + 65536;
    int*   counts  = (int*)(ws + 65600);
    int*   lists   = (int*)d_out;
    float* out     = (float*)d_out;

    init_centers<<<64, 256, 0, stream>>>(x, centers, c2);
    for (int it = 0; it < ITERS; ++it) {
        hipMemsetAsync(counts, 0, K_CL * sizeof(int), stream);
        hipMemsetAsync(sums, 0, K_CL * DIM * sizeof(float), stream);
        assign_scatter<<<512, 256, 0, stream>>>(x, centers, c2, counts, lists);
        gather_sums<<<dim3(64, 4, 8), 128, 0, stream>>>(x, lists, counts, sums);
        update_centers<<<64, 256, 0, stream>>>(centers, sums, counts, c2);
    }
    final_dist<<<512, 256, 0, stream>>>(x, centers, out);
}

// Round 2
// 1873.346 us; speedup vs baseline: 1.0179x; 1.0179x over previous
//
#include <hip/hip_runtime.h>
#include <math.h>

#define N_PTS 32768
#define DIM   512
#define K_CL  64
#define ITERS 10
#define EPS_F 1e-8f

// ---------------------------------------------------------------------------
// ws layout (floats):
//   ct:     [0, 32768)       transposed centers, ct[d*64 + k]  (512 x 64)
//   sums:   [32768, 65536)   row-major sums[k*512 + d]         (64 x 512)
//   c2:     [65536, 65600)   per-cluster squared norm
//   counts: int32 at float offset 65600, 64 ints
// d_out doubles as per-cluster index lists during iterations.
// ---------------------------------------------------------------------------

__global__ void init_centers(const float* __restrict__ x,
                             float* __restrict__ ct,
                             float* __restrict__ c2) {
    int k = blockIdx.x;      // 0..63
    int t = threadIdx.x;     // 0..255
    float ssum = 0.f;
    for (int d = t; d < DIM; d += 256) {
        float v = x[k * DIM + d];
        ct[d * K_CL + k] = v;
        ssum += v * v;
    }
    #pragma unroll
    for (int off = 32; off; off >>= 1) ssum += __shfl_down(ssum, off);
    __shared__ float red[4];
    if ((t & 63) == 0) red[t >> 6] = ssum;
    __syncthreads();
    if (t == 0) c2[k] = red[0] + red[1] + red[2] + red[3];
}

// 32 points x 64 clusters per block. Centers staged from transposed ct
// (contiguous, conflict-free); x read directly from global (L1 broadcast).
// Dot accumulation order is bitwise-identical to the round-1 kernel.
__launch_bounds__(128)
__global__ void assign_scatter(const float* __restrict__ x,
                               const float* __restrict__ ct,
                               const float* __restrict__ c2,
                               int* __restrict__ counts,
                               int* __restrict__ lists) {
    __shared__ float cs[2][32 * K_CL];   // 2 x 8 KB double buffer
    __shared__ float c2s[K_CL];

    const int tid = threadIdx.x;
    const int pbase = blockIdx.x * 32;
    const int r = tid >> 4;   // 0..7 : point group (4 pts)
    const int c = tid & 15;   // 0..15: cluster group (4 cl)
    if (tid < K_CL) c2s[tid] = c2[tid];

    float4 sr0, sr1, sr2, sr3;
#define LOADREG(t_) { const float* p_ = ct + (t_) * 32 * K_CL + tid * 4;      \
        sr0 = *(const float4*)(p_);        sr1 = *(const float4*)(p_ + 512);  \
        sr2 = *(const float4*)(p_ + 1024); sr3 = *(const float4*)(p_ + 1536); }
#define STOREREG(b_) { float* q_ = &cs[b_][tid * 4];                          \
        *(float4*)(q_)        = sr0; *(float4*)(q_ + 512)  = sr1;             \
        *(float4*)(q_ + 1024) = sr2; *(float4*)(q_ + 1536) = sr3; }

    LOADREG(0); STOREREG(0); LOADREG(1);
    __syncthreads();

    float acc[4][4] = {};
    const float* xb = x + (size_t)(pbase + r * 4) * DIM;

    int buf = 0;
    for (int t = 0; t < 16; ++t) {
        if (t < 15) { STOREREG(buf ^ 1); }
        if (t < 14) { LOADREG(t + 2); }
        const float* cb = cs[buf];
        #pragma unroll
        for (int kkq = 0; kkq < 8; ++kkq) {
            const int d0 = t * 32 + kkq * 4;
            float4 xva[4];
            #pragma unroll
            for (int i = 0; i < 4; ++i)
                xva[i] = *(const float4*)(xb + i * DIM + d0);
            float4 cv0 = *(const float4*)(cb + (kkq * 4 + 0) * K_CL + c * 4);
            float4 cv1 = *(const float4*)(cb + (kkq * 4 + 1) * K_CL + c * 4);
            float4 cv2 = *(const float4*)(cb + (kkq * 4 + 2) * K_CL + c * 4);
            float4 cv3 = *(const float4*)(cb + (kkq * 4 + 3) * K_CL + c * 4);
            #pragma unroll
            for (int i = 0; i < 4; ++i) {
                // dims strictly ascending per acc[i][j] (bitwise == round 1)
                acc[i][0] += xva[i].x * cv0.x; acc[i][1] += xva[i].x * cv0.y;
                acc[i][2] += xva[i].x * cv0.z; acc[i][3] += xva[i].x * cv0.w;
                acc[i][0] += xva[i].y * cv1.x; acc[i][1] += xva[i].y * cv1.y;
                acc[i][2] += xva[i].y * cv1.z; acc[i][3] += xva[i].y * cv1.w;
                acc[i][0] += xva[i].z * cv2.x; acc[i][1] += xva[i].z * cv2.y;
                acc[i][2] += xva[i].z * cv2.z; acc[i][3] += xva[i].z * cv2.w;
                acc[i][0] += xva[i].w * cv3.x; acc[i][1] += xva[i].w * cv3.y;
                acc[i][2] += xva[i].w * cv3.z; acc[i][3] += xva[i].w * cv3.w;
            }
        }
        __syncthreads();
        buf ^= 1;
    }

    #pragma unroll
    for (int i = 0; i < 4; ++i) {
        float bv = 1e30f; int bc = 0;
        #pragma unroll
        for (int j = 0; j < 4; ++j) {
            float v = c2s[c * 4 + j] - 2.0f * acc[i][j];
            if (v < bv) { bv = v; bc = c * 4 + j; }
        }
        #pragma unroll
        for (int m = 1; m < 16; m <<= 1) {
            float ov = __shfl_xor(bv, m);
            int   oc = __shfl_xor(bc, m);
            if (ov < bv || (ov == bv && oc < bc)) { bv = ov; bc = oc; }
        }
        if (c == 0) {
            int p = pbase + r * 4 + i;
            int slot = atomicAdd(&counts[bc], 1);
            lists[bc * N_PTS + slot] = p;
        }
    }
}

__global__ void gather_sums(const float* __restrict__ x,
                            const int* __restrict__ lists,
                            const int* __restrict__ counts,
                            float* __restrict__ sums) {
    int k  = blockIdx.x;
    int dc = blockIdx.y;
    int pc = blockIdx.z;
    int t  = threadIdx.x;
    int n  = counts[k];
    int s0 = (n * pc) >> 3;
    int s1 = (n * (pc + 1)) >> 3;
    int d  = dc * 128 + t;
    const int* lst = lists + k * N_PTS;
    float acc = 0.f;
    int s = s0;
    for (; s + 8 <= s1; s += 8) {
        int idx[8];
        #pragma unroll
        for (int q = 0; q < 8; ++q) idx[q] = lst[s + q];
        #pragma unroll
        for (int q = 0; q < 8; ++q) acc += x[(size_t)idx[q] * DIM + d];
    }
    for (; s < s1; ++s) acc += x[(size_t)lst[s] * DIM + d];
    atomicAdd(&sums[k * DIM + d], acc);
}

__global__ void update_centers(float* __restrict__ ct,
                               const float* __restrict__ sums,
                               const int* __restrict__ counts,
                               float* __restrict__ c2) {
    int k = blockIdx.x;
    int t = threadIdx.x;
    int cnt = counts[k];
    float fc = (float)cnt;
    float ssum = 0.f;
    for (int d = t; d < DIM; d += 256) {
        float v = ct[d * K_CL + k];
        if (cnt > 0) v = sums[k * DIM + d] / fc;
        ct[d * K_CL + k] = v;
        ssum += v * v;
    }
    #pragma unroll
    for (int off = 32; off; off >>= 1) ssum += __shfl_down(ssum, off);
    __shared__ float red[4];
    if ((t & 63) == 0) red[t >> 6] = ssum;
    __syncthreads();
    if (t == 0) c2[k] = red[0] + red[1] + red[2] + red[3];
}

// Final distances via direct differencing (exact 0 at singletons).
__launch_bounds__(128)
__global__ void final_dist(const float* __restrict__ x,
                           const float* __restrict__ ct,
                           float* __restrict__ out) {
    __shared__ float cs[2][32 * K_CL];

    const int tid = threadIdx.x;
    const int pbase = blockIdx.x * 32;
    const int r = tid >> 4;
    const int c = tid & 15;

    float4 sr0, sr1, sr2, sr3;
    LOADREG(0); STOREREG(0); LOADREG(1);
    __syncthreads();

    float acc[4][4] = {};
    const float* xb = x + (size_t)(pbase + r * 4) * DIM;

    int buf = 0;
    for (int t = 0; t < 16; ++t) {
        if (t < 15) { STOREREG(buf ^ 1); }
        if (t < 14) { LOADREG(t + 2); }
        const float* cb = cs[buf];
        #pragma unroll
        for (int kkq = 0; kkq < 8; ++kkq) {
            const int d0 = t * 32 + kkq * 4;
            float4 xva[4];
            #pragma unroll
            for (int i = 0; i < 4; ++i)
                xva[i] = *(const float4*)(xb + i * DIM + d0);
            float4 cv0 = *(const float4*)(cb + (kkq * 4 + 0) * K_CL + c * 4);
            float4 cv1 = *(const float4*)(cb + (kkq * 4 + 1) * K_CL + c * 4);
            float4 cv2 = *(const float4*)(cb + (kkq * 4 + 2) * K_CL + c * 4);
            float4 cv3 = *(const float4*)(cb + (kkq * 4 + 3) * K_CL + c * 4);
            #pragma unroll
            for (int i = 0; i < 4; ++i) {
                float xq[4] = {xva[i].x, xva[i].y, xva[i].z, xva[i].w};
                float cq[4][4] = {{cv0.x, cv0.y, cv0.z, cv0.w},
                                  {cv1.x, cv1.y, cv1.z, cv1.w},
                                  {cv2.x, cv2.y, cv2.z, cv2.w},
                                  {cv3.x, cv3.y, cv3.z, cv3.w}};
                #pragma unroll
                for (int m = 0; m < 4; ++m)
                    #pragma unroll
                    for (int j = 0; j < 4; ++j) {
                        float dlt = xq[m] - cq[m][j];
                        acc[i][j] += dlt * dlt;
                    }
            }
        }
        __syncthreads();
        buf ^= 1;
    }

    #pragma unroll
    for (int i = 0; i < 4; ++i) {
        int p = pbase + r * 4 + i;
        float4 o;
        o.x = 1.0f / (sqrtf(acc[i][0]) + EPS_F);
        o.y = 1.0f / (sqrtf(acc[i][1]) + EPS_F);
        o.z = 1.0f / (sqrtf(acc[i][2]) + EPS_F);
        o.w = 1.0f / (sqrtf(acc[i][3]) + EPS_F);
        *(float4*)(out + (size_t)p * K_CL + c * 4) = o;
    }
}

extern "C" void kernel_launch(void* const* d_in, const int* in_sizes, int n_in,
                              void* d_out, int out_size, void* d_ws, size_t ws_size,
                              hipStream_t stream) {
    (void)in_sizes; (void)n_in; (void)out_size; (void)ws_size;
    const float* x = (const float*)d_in[0];
    float* ws      = (float*)d_ws;
    float* ct      = ws;
    float* sums    = ws + 32768;
    float* c2      = ws + 65536;
    int*   counts  = (int*)(ws + 65600);
    int*   lists   = (int*)d_out;
    float* out     = (float*)d_out;

    init_centers<<<64, 256, 0, stream>>>(x, ct, c2);
    for (int it = 0; it < ITERS; ++it) {
        hipMemsetAsync(counts, 0, K_CL * sizeof(int), stream);
        hipMemsetAsync(sums, 0, K_CL * DIM * sizeof(float), stream);
        assign_scatter<<<1024, 128, 0, stream>>>(x, ct, c2, counts, lists);
        gather_sums<<<dim3(64, 4, 8), 128, 0, stream>>>(x, lists, counts, sums);
        update_centers<<<64, 256, 0, stream>>>(ct, sums, counts, c2);
    }
    final_dist<<<1024, 128, 0, stream>>>(x, ct, out);
}